// Round 11
// baseline (61.826 us; speedup 1.0000x reference)
//
#include <hip/hip_runtime.h>
#include <stdint.h>

#define NTOK 2048
#define DMODEL 256
#define NHEAD 4

typedef __attribute__((ext_vector_type(8))) short short8;
typedef __attribute__((ext_vector_type(4))) float f32x4;

#define MFMA16(a, b, c) __builtin_amdgcn_mfma_f32_16x16x32_bf16(a, b, c, 0, 0, 0)

#if __has_builtin(__builtin_amdgcn_exp2f)
#define EXP2(x) __builtin_amdgcn_exp2f(x)
#else
#define EXP2(x) __expf((x) * 0.6931471805599453f)
#endif

__device__ __forceinline__ unsigned short f2bf(float f) {
  union { float f; unsigned int u; } v; v.f = f;
  unsigned int r = v.u + 0x7FFFu + ((v.u >> 16) & 1u);
  return (unsigned short)(r >> 16);
}

__device__ __forceinline__ f32x4 zero4() {
  f32x4 v; v[0] = 0.f; v[1] = 0.f; v[2] = 0.f; v[3] = 0.f; return v;
}

// load 8 consecutive f32 and pack to bf16x8 (RNE via v_cvt_pk_bf16_f32)
__device__ __forceinline__ short8 cvt8(const float* p) {
  float4 lo = *(const float4*)p;
  float4 hi = *(const float4*)(p + 4);
  union { short8 s8; unsigned int u[4]; } r;
  asm("v_cvt_pk_bf16_f32 %0, %1, %2" : "=v"(r.u[0]) : "v"(lo.x), "v"(lo.y));
  asm("v_cvt_pk_bf16_f32 %0, %1, %2" : "=v"(r.u[1]) : "v"(lo.z), "v"(lo.w));
  asm("v_cvt_pk_bf16_f32 %0, %1, %2" : "=v"(r.u[2]) : "v"(hi.x), "v"(hi.y));
  asm("v_cvt_pk_bf16_f32 %0, %1, %2" : "=v"(r.u[3]) : "v"(hi.z), "v"(hi.w));
  return r.s8;
}

// ---------------- kernel 1: bf16 conversion of W, Wo only (128 blocks, ~0.5us) ----------------
__global__ void k_prep(const float* __restrict__ W, const float* __restrict__ Wo,
                       unsigned short* __restrict__ Wbf, unsigned short* __restrict__ Wobf) {
  int e = (blockIdx.x * 256 + threadIdx.x) * 4;
  const float* s; unsigned short* d; int off;
  if (e < 65536) { s = W;  d = Wbf;  off = e; }
  else           { s = Wo; d = Wobf; off = e - 65536; }
  float4 v = *(const float4*)(s + off);
  ushort4 o;
  o.x = f2bf(v.x); o.y = f2bf(v.y); o.z = f2bf(v.z); o.w = f2bf(v.w);
  *(ushort4*)(d + off) = o;
}

// ---------------- kernel 2: fused {h = x@W^T -> hTg + src/dst} and {adj bit-pack} ----------------
// blocks [0,512): gemm1 (A-side: f32 x + in-register cvt8; B-side: prepped Wbf);
// blocks [512,4608): adj pack. hTg fragment-native layout: [bh][c=j/32][dh][klg][8j].
__global__ __launch_bounds__(256) void k_g1p(
    const float* __restrict__ x, const unsigned short* __restrict__ Wbf,
    const float* __restrict__ a_src, const float* __restrict__ a_dst,
    const int* __restrict__ adj,
    unsigned short* __restrict__ hTg, float* __restrict__ srcv, float* __restrict__ dstv,
    unsigned long long* __restrict__ bits) {
  __shared__ float tile[64][65];
  __shared__ float reds[2][4][64];
  const int b = blockIdx.x;
  if (b >= 512) {  // ---- adj pack: 4096 blocks x 1024 elems ----
    const int base = (b - 512) * 1024 + threadIdx.x;
#pragma unroll
    for (int r = 0; r < 4; ++r) {
      int g = base + r * 256;
      unsigned long long m = __ballot(adj[g] > 0);
      if ((threadIdx.x & 63) == 0) bits[g >> 6] = m;
    }
    return;
  }
  // ---- gemm1: 64 g-rows x 64 cols (head hh) ----
  const int tid = threadIdx.x, lane = tid & 63, w = tid >> 6;
  const int g0 = (b & 127) * 64;
  const int hh = b >> 7;
  const int n0 = hh * 64;
  const int l15 = lane & 15, kl = (lane >> 4) * 8;

  const float* arow = x + (size_t)(g0 + w * 16 + l15) * 256 + kl;
  const unsigned short* brow = Wbf + (size_t)(n0 + l15) * 256 + kl;

  f32x4 acc[4];
#pragma unroll
  for (int nf = 0; nf < 4; ++nf) acc[nf] = zero4();

#pragma unroll
  for (int k = 0; k < 256; k += 32) {
    short8 a = cvt8(arow + k);
#pragma unroll
    for (int nf = 0; nf < 4; ++nf) {
      short8 bb = *(const short8*)(brow + nf * 4096 + k);
      acc[nf] = MFMA16(a, bb, acc[nf]);
    }
  }

  const int rbase = w * 16 + (lane >> 4) * 4;
#pragma unroll
  for (int nf = 0; nf < 4; ++nf)
#pragma unroll
    for (int r = 0; r < 4; ++r)
      tile[rbase + r][nf * 16 + l15] = acc[nf][r];
  __syncthreads();

  const int bh = (g0 >> 11) * NHEAD + hh;
  // fragment-native bf16 write
  {
    const int dh = tid >> 2, nq = (tid & 3) * 16;
    const int c = ((g0 & 2047) + nq) >> 5;   // 32-j chunk within bh
    const int k0 = (nq & 16) >> 3;           // klg = 0 or 2 (v1 takes klg+1)
    unsigned short* dp = hTg + (size_t)bh * 131072 + c * 2048 + dh * 32 + k0 * 8;
    short8 v0, v1;
#pragma unroll
    for (int q = 0; q < 8; ++q) v0[q] = (short)f2bf(tile[nq + q][dh]);
#pragma unroll
    for (int q = 0; q < 8; ++q) v1[q] = (short)f2bf(tile[nq + 8 + q][dh]);
    *(short8*)dp = v0;
    *(short8*)(dp + 8) = v1;
  }
  // src/dst partial dot over dh
  {
    const int n_loc = tid & 63, q4 = tid >> 6;
    const float* as = a_src + hh * 64 + q4 * 16;
    const float* ad = a_dst + hh * 64 + q4 * 16;
    float ps = 0.f, pd = 0.f;
#pragma unroll
    for (int d2 = 0; d2 < 16; ++d2) {
      float hv = tile[n_loc][q4 * 16 + d2];
      ps += hv * as[d2];
      pd += hv * ad[d2];
    }
    reds[0][q4][n_loc] = ps;
    reds[1][q4][n_loc] = pd;
  }
  __syncthreads();
  if (tid < 64) {
    float s = reds[0][0][tid] + reds[0][1][tid] + reds[0][2][tid] + reds[0][3][tid];
    float d = reds[1][0][tid] + reds[1][1][tid] + reds[1][2][tid] + reds[1][3][tid];
    srcv[(size_t)bh * 2048 + (g0 & 2047) + tid] = s;
    dstv[(size_t)bh * 2048 + (g0 & 2047) + tid] = d;
  }
}

// ---------------- kernel 3: masked GAT attention (R7/R9 proven body + setprio) ----------------
// L2-direct kv (fragment-native hTg, contiguous 1KB wave-loads), no main-loop barriers.
// Max-form exp-free scores: p = mask ? max(A_i*B_j, C_i*D_j) : 0.
// __launch_bounds__(512,4): VGPR budget 128 — do NOT raise min-waves (R8: 295MB spill).
__global__ __launch_bounds__(512, 4) void k_attn(
    const unsigned short* __restrict__ hTg, const float* __restrict__ srcv,
    const float* __restrict__ dstv, const unsigned long long* __restrict__ bits,
    unsigned short* __restrict__ attb) {
  __shared__ float bB_s[2048];
  __shared__ float dD_s[2048];
  __shared__ unsigned long long adjw[64][33];
  __shared__ float src_s[64];
  __shared__ float red[8];
  __shared__ float comb[2][64][40];

  const int tid = threadIdx.x, lane = tid & 63, w = tid >> 6;
  const int orig = blockIdx.x;
  const int lid = (orig & 7) * 64 + (orig >> 3);  // XCD-bijective: 2 bh per XCD
  const int bh = lid >> 5;
  const int i0 = (lid & 31) * 64;
  const int rg = w & 1, js = w >> 1;
  const float LOG2E = 1.4426950408889634f;

  // ---- preamble: B/D tables + global dst max, src (scaled), adj words ----
  float lmax = -3.0e38f;
  {
    const float* dsrc = dstv + (size_t)bh * 2048;
    int idx = tid * 4;
    float4 v = *(const float4*)(dsrc + idx);
    v.x *= LOG2E; v.y *= LOG2E; v.z *= LOG2E; v.w *= LOG2E;
    lmax = fmaxf(fmaxf(v.x, v.y), fmaxf(v.z, v.w));
    float4 Bv, Dv;
    Bv.x = EXP2(v.x); Bv.y = EXP2(v.y); Bv.z = EXP2(v.z); Bv.w = EXP2(v.w);
    Dv.x = EXP2(0.2f * v.x); Dv.y = EXP2(0.2f * v.y);
    Dv.z = EXP2(0.2f * v.z); Dv.w = EXP2(0.2f * v.w);
    *(float4*)(bB_s + idx) = Bv;
    *(float4*)(dD_s + idx) = Dv;
#pragma unroll
    for (int off = 32; off >= 1; off >>= 1) lmax = fmaxf(lmax, __shfl_xor(lmax, off));
    if (lane == 0) red[w] = lmax;
    if (tid < 64) src_s[tid] = srcv[(size_t)bh * 2048 + i0 + tid] * LOG2E;
#pragma unroll
    for (int t = 0; t < 4; ++t) {
      int q = tid + t * 512;  // 0..2047
      adjw[q >> 5][q & 31] = bits[(size_t)(i0 + (q >> 5)) * 32 + (q & 31)];
    }
  }
  __syncthreads();
  const float dmax = fmaxf(fmaxf(fmaxf(red[0], red[1]), fmaxf(red[2], red[3])),
                           fmaxf(fmaxf(red[4], red[5]), fmaxf(red[6], red[7])));

  const int l15 = lane & 15, klg = lane >> 4, kl = klg * 8;
  const float src0 = src_s[rg * 32 + l15];
  const float src1 = src_s[rg * 32 + 16 + l15];
  const float sa0 = src0 + dmax, sa1 = src1 + dmax;
  const float m0 = fmaxf(sa0, 0.2f * sa0);  // scaled leaky upper bound of row max
  const float m1 = fmaxf(sa1, 0.2f * sa1);
  const float A0 = EXP2(src0 - m0), C0 = EXP2(fmaf(0.2f, src0, -m0));
  const float A1 = EXP2(src1 - m1), C1 = EXP2(fmaf(0.2f, src1, -m1));
  const int il0 = rg * 32 + l15, il1 = il0 + 16;
  const int wsel = js >> 1, wsh = (js & 1) * 32 + kl;

  const unsigned short* hgb = hTg + (size_t)bh * 131072;
  const int fragoff = l15 * 32 + klg * 8;  // +nf*512 per dh-quadrant

  short8 ones;
#pragma unroll
  for (int q = 0; q < 8; ++q) ones[q] = (short)0x3F80;

  f32x4 acc[2][4], accs[2];
#pragma unroll
  for (int rh = 0; rh < 2; ++rh) {
    accs[rh] = zero4();
#pragma unroll
    for (int nf = 0; nf < 4; ++nf) acc[rh][nf] = zero4();
  }

  // preload tile 0 fragments (contiguous 1KB wave-loads from L2)
  short8 pA0, pA1, pA2, pA3, pB0, pB1, pB2, pB3;
  {
    const unsigned short* kp = hgb + js * 2048 + fragoff;
    pA0 = *(const short8*)(kp);
    pA1 = *(const short8*)(kp + 512);
    pA2 = *(const short8*)(kp + 1024);
    pA3 = *(const short8*)(kp + 1536);
  }

#define GAT_TILE(T, C0_, C1_, C2_, C3_, N0_, N1_, N2_, N3_)                       \
  {                                                                               \
    if ((T) < 15) {                                                               \
      const unsigned short* kp = hgb + (((T) + 1) * 4 + js) * 2048 + fragoff;     \
      N0_ = *(const short8*)(kp);                                                 \
      N1_ = *(const short8*)(kp + 512);                                           \
      N2_ = *(const short8*)(kp + 1024);                                          \
      N3_ = *(const short8*)(kp + 1536);                                          \
    }                                                                             \
    const int jo = (T) * 128 + js * 32 + kl;                                      \
    float4 b0 = *(const float4*)(bB_s + jo);                                      \
    float4 b1 = *(const float4*)(bB_s + jo + 4);                                  \
    float4 e0 = *(const float4*)(dD_s + jo);                                      \
    float4 e1 = *(const float4*)(dD_s + jo + 4);                                  \
    float bv[8] = {b0.x, b0.y, b0.z, b0.w, b1.x, b1.y, b1.z, b1.w};               \
    float dq[8] = {e0.x, e0.y, e0.z, e0.w, e1.x, e1.y, e1.z, e1.w};               \
    const unsigned long long w0_ = adjw[il0][2 * (T) + wsel];                     \
    const unsigned long long w1_ = adjw[il1][2 * (T) + wsel];                     \
    {                                                                             \
      const unsigned int byte = (unsigned int)(w0_ >> wsh) & 0xFFu;               \
      float p[8];                                                                 \
      _Pragma("unroll") for (int t8 = 0; t8 < 8; ++t8) {                          \
        const float pv = fmaxf(A0 * bv[t8], C0 * dq[t8]);                         \
        p[t8] = ((byte >> t8) & 1u) ? pv : 0.f;                                   \
      }                                                                           \
      union { short8 s8; unsigned int u32[4]; } af;                               \
      _Pragma("unroll") for (int q = 0; q < 4; ++q)                               \
        asm("v_cvt_pk_bf16_f32 %0, %1, %2"                                       \
            : "=v"(af.u32[q]) : "v"(p[2 * q]), "v"(p[2 * q + 1]));                \
      __builtin_amdgcn_s_setprio(1);                                              \
      accs[0] = MFMA16(af.s8, ones, accs[0]);                                     \
      acc[0][0] = MFMA16(af.s8, C0_, acc[0][0]);                                  \
      acc[0][1] = MFMA16(af.s8, C1_, acc[0][1]);                                  \
      acc[0][2] = MFMA16(af.s8, C2_, acc[0][2]);                                  \
      acc[0][3] = MFMA16(af.s8, C3_, acc[0][3]);                                  \
      __builtin_amdgcn_s_setprio(0);                                              \
    }                                                                             \
    {                                                                             \
      const unsigned int byte = (unsigned int)(w1_ >> wsh) & 0xFFu;               \
      float p[8];                                                                 \
      _Pragma("unroll") for (int t8 = 0; t8 < 8; ++t8) {                          \
        const float pv = fmaxf(A1 * bv[t8], C1 * dq[t8]);                         \
        p[t8] = ((byte >> t8) & 1u) ? pv : 0.f;                                   \
      }                                                                           \
      union { short8 s8; unsigned int u32[4]; } af;                               \
      _Pragma("unroll") for (int q = 0; q < 4; ++q)                               \
        asm("v_cvt_pk_bf16_f32 %0, %1, %2"                                       \
            : "=v"(af.u32[q]) : "v"(p[2 * q]), "v"(p[2 * q + 1]));                \
      __builtin_amdgcn_s_setprio(1);                                              \
      accs[1] = MFMA16(af.s8, ones, accs[1]);                                     \
      acc[1][0] = MFMA16(af.s8, C0_, acc[1][0]);                                  \
      acc[1][1] = MFMA16(af.s8, C1_, acc[1][1]);                                  \
      acc[1][2] = MFMA16(af.s8, C2_, acc[1][2]);                                  \
      acc[1][3] = MFMA16(af.s8, C3_, acc[1][3]);                                  \
      __builtin_amdgcn_s_setprio(0);                                              \
    }                                                                             \
  }

#pragma unroll 1
  for (int tt = 0; tt < 16; tt += 2) {
    GAT_TILE(tt, pA0, pA1, pA2, pA3, pB0, pB1, pB2, pB3);
    GAT_TILE(tt + 1, pB0, pB1, pB2, pB3, pA0, pA1, pA2, pA3);
  }
#undef GAT_TILE

  // ---- combine j-slices (js=1..3 into js=0) ----
#pragma unroll 1
  for (int s = 1; s < 4; ++s) {
    if (js == s) {
#pragma unroll
      for (int rh = 0; rh < 2; ++rh) {
#pragma unroll
        for (int nf = 0; nf < 4; ++nf)
#pragma unroll
          for (int r = 0; r < 4; ++r) comb[rg][lane][rh * 20 + nf * 4 + r] = acc[rh][nf][r];
#pragma unroll
        for (int r = 0; r < 4; ++r) comb[rg][lane][rh * 20 + 16 + r] = accs[rh][r];
      }
    }
    __syncthreads();
    if (js == 0) {
#pragma unroll
      for (int rh = 0; rh < 2; ++rh) {
#pragma unroll
        for (int nf = 0; nf < 4; ++nf)
#pragma unroll
          for (int r = 0; r < 4; ++r) acc[rh][nf][r] += comb[rg][lane][rh * 20 + nf * 4 + r];
#pragma unroll
        for (int r = 0; r < 4; ++r) accs[rh][r] += comb[rg][lane][rh * 20 + 16 + r];
      }
    }
    __syncthreads();
  }

  // ---- epilogue: normalize + store (js==0 waves only) ----
  if (js == 0) {
    const int rb = klg * 4;
    const int b = bh >> 2, hh2 = bh & 3;
#pragma unroll
    for (int rh = 0; rh < 2; ++rh) {
      float linv[4];
#pragma unroll
      for (int r = 0; r < 4; ++r) linv[r] = 1.f / accs[rh][r];
#pragma unroll
      for (int nf = 0; nf < 4; ++nf)
#pragma unroll
        for (int r = 0; r < 4; ++r) {
          int i = i0 + rg * 32 + rh * 16 + rb + r;
          size_t o = ((size_t)(b * 2048 + i)) * 256 + hh2 * 64 + nf * 16 + l15;
          attb[o] = f2bf(acc[rh][nf][r] * linv[r]);
        }
    }
  }
}

// ---------------- kernel 4: out2 = att @ Wo^T + bo; y = LN(x + out2) ----------------
__global__ void k_gemm2(const unsigned short* __restrict__ attb, const unsigned short* __restrict__ Wobf,
                        const float* __restrict__ bo, const float* __restrict__ x,
                        const float* __restrict__ gamma, const float* __restrict__ beta,
                        float* __restrict__ out) {
  __shared__ float tile[32][260];
  const int tid = threadIdx.x, lane = tid & 63, w = tid >> 6;
  const int g0 = blockIdx.x * 32;
  const int l15 = lane & 15, kl = (lane >> 4) * 8;
  const int rw = (w & 1) * 16;
  const int cb = (w >> 1) * 128;

  const unsigned short* arow = attb + (size_t)(g0 + rw + l15) * 256 + kl;
  const unsigned short* brow = Wobf + (size_t)(cb + l15) * 256 + kl;

  f32x4 acc[8];
#pragma unroll
  for (int nf = 0; nf < 8; ++nf) acc[nf] = zero4();

#pragma unroll
  for (int k = 0; k < 256; k += 32) {
    short8 a = *(const short8*)(arow + k);
#pragma unroll
    for (int nf = 0; nf < 8; ++nf) {
      short8 b = *(const short8*)(brow + (size_t)nf * 4096 + k);
      acc[nf] = MFMA16(a, b, acc[nf]);
    }
  }

  const int rb = rw + (lane >> 4) * 4;
#pragma unroll
  for (int nf = 0; nf < 8; ++nf)
#pragma unroll
    for (int r = 0; r < 4; ++r) {
      int c = cb + nf * 16 + l15;
      tile[rb + r][c] = acc[nf][r] + bo[c];
    }
  __syncthreads();

  const float4 gv = *(const float4*)(gamma + lane * 4);
  const float4 bv = *(const float4*)(beta + lane * 4);
  for (int r = 0; r < 8; ++r) {
    const int gl = w * 8 + r;
    const size_t g = g0 + gl;
    float4 xv = *(const float4*)(x + g * 256 + lane * 4);
    float4 tv = *(float4*)(&tile[gl][lane * 4]);
    float v0 = tv.x + xv.x, v1 = tv.y + xv.y, v2 = tv.z + xv.z, v3 = tv.w + xv.w;
    float sum = v0 + v1 + v2 + v3;
    float sq = v0 * v0 + v1 * v1 + v2 * v2 + v3 * v3;
#pragma unroll
    for (int off = 32; off >= 1; off >>= 1) {
      sum += __shfl_xor(sum, off);
      sq += __shfl_xor(sq, off);
    }
    const float mu = sum * (1.f / 256.f);
    const float var = sq * (1.f / 256.f) - mu * mu;
    const float rs = rsqrtf(var + 1e-5f);
    float4 o;
    o.x = (v0 - mu) * rs * gv.x + bv.x;
    o.y = (v1 - mu) * rs * gv.y + bv.y;
    o.z = (v2 - mu) * rs * gv.z + bv.z;
    o.w = (v3 - mu) * rs * gv.w + bv.w;
    *(float4*)(out + g * 256 + lane * 4) = o;
  }
}

extern "C" void kernel_launch(void* const* d_in, const int* in_sizes, int n_in,
                              void* d_out, int out_size, void* d_ws, size_t ws_size,
                              hipStream_t stream) {
  const float* x      = (const float*)d_in[0];
  const int*   adj    = (const int*)d_in[1];
  const float* W      = (const float*)d_in[2];
  const float* a_src  = (const float*)d_in[3];
  const float* a_dst  = (const float*)d_in[4];
  const float* Wo     = (const float*)d_in[5];
  const float* bo     = (const float*)d_in[6];
  const float* gamma  = (const float*)d_in[7];
  const float* beta   = (const float*)d_in[8];
  float* out = (float*)d_out;

  char* ws = (char*)d_ws;
  unsigned short* hTg       = (unsigned short*)(ws + (4u << 20));
  unsigned short* attb      = (unsigned short*)(ws + (8u << 20));
  unsigned long long* bits  = (unsigned long long*)(ws + (12u << 20));
  unsigned short* Wbf       = (unsigned short*)(ws + (12u << 20) + (512u << 10));
  unsigned short* Wobf      = (unsigned short*)(ws + (12u << 20) + (640u << 10));
  float* srcv               = (float*)(ws + (12u << 20) + (768u << 10));
  float* dstv               = (float*)(ws + (12u << 20) + (896u << 10));

  k_prep<<<128, 256, 0, stream>>>(W, Wo, Wbf, Wobf);
  k_g1p<<<4608, 256, 0, stream>>>(x, Wbf, a_src, a_dst, adj, hTg, srcv, dstv, bits);
  k_attn<<<512, 512, 0, stream>>>(hTg, srcv, dstv, bits, attb);
  k_gemm2<<<256, 256, 0, stream>>>(attb, Wobf, bo, x, gamma, beta, out);
}

// Round 13
// 60.443 us; speedup vs baseline: 1.0229x; 1.0229x over previous
//
#include <hip/hip_runtime.h>
#include <stdint.h>

#define NTOK 2048
#define DMODEL 256
#define NHEAD 4

typedef __attribute__((ext_vector_type(8))) short short8;
typedef __attribute__((ext_vector_type(4))) float f32x4;

#define MFMA16(a, b, c) __builtin_amdgcn_mfma_f32_16x16x32_bf16(a, b, c, 0, 0, 0)

#if __has_builtin(__builtin_amdgcn_exp2f)
#define EXP2(x) __builtin_amdgcn_exp2f(x)
#else
#define EXP2(x) __expf((x) * 0.6931471805599453f)
#endif

__device__ __forceinline__ unsigned short f2bf(float f) {
  union { float f; unsigned int u; } v; v.f = f;
  unsigned int r = v.u + 0x7FFFu + ((v.u >> 16) & 1u);
  return (unsigned short)(r >> 16);
}

__device__ __forceinline__ f32x4 zero4() {
  f32x4 v; v[0] = 0.f; v[1] = 0.f; v[2] = 0.f; v[3] = 0.f; return v;
}

// ---------------- kernel 1: bf16 conversion of x, W, Wo ----------------
__global__ void k_prep(const float* __restrict__ x, const float* __restrict__ W,
                       const float* __restrict__ Wo,
                       unsigned short* __restrict__ xbf, unsigned short* __restrict__ Wbf,
                       unsigned short* __restrict__ Wobf) {
  int e = (blockIdx.x * 256 + threadIdx.x) * 4;
  const float* s; unsigned short* d; int off;
  if (e < 2097152)              { s = x;  d = xbf;  off = e; }
  else if (e < 2097152 + 65536) { s = W;  d = Wbf;  off = e - 2097152; }
  else                          { s = Wo; d = Wobf; off = e - 2162688; }
  float4 v = *(const float4*)(s + off);
  ushort4 o;
  o.x = f2bf(v.x); o.y = f2bf(v.y); o.z = f2bf(v.z); o.w = f2bf(v.w);
  *(ushort4*)(d + off) = o;
}

// ---------------- kernel 2: fused {h = x@W^T -> hTg + src/dst} and {adj bit-pack} ----------------
// blocks [0,512): gemm1 (bf16 inputs); blocks [512,4608): adj pack.
// hTg fragment-native layout: [bh][c=j/32][dh][klg=jsub/8][8 j] so an attention
// B-frag wave-load is one contiguous 1KB global read.
__global__ __launch_bounds__(256) void k_g1p(
    const unsigned short* __restrict__ xbf, const unsigned short* __restrict__ Wbf,
    const float* __restrict__ a_src, const float* __restrict__ a_dst,
    const int* __restrict__ adj,
    unsigned short* __restrict__ hTg, float* __restrict__ srcv, float* __restrict__ dstv,
    unsigned long long* __restrict__ bits) {
  __shared__ float tile[64][65];
  __shared__ float reds[2][4][64];
  const int b = blockIdx.x;
  if (b >= 512) {  // ---- adj pack: 4096 blocks x 1024 elems ----
    const int base = (b - 512) * 1024 + threadIdx.x;
#pragma unroll
    for (int r = 0; r < 4; ++r) {
      int g = base + r * 256;
      unsigned long long m = __ballot(adj[g] > 0);
      if ((threadIdx.x & 63) == 0) bits[g >> 6] = m;
    }
    return;
  }
  // ---- gemm1: 64 g-rows x 64 cols (head hh) ----
  const int tid = threadIdx.x, lane = tid & 63, w = tid >> 6;
  const int g0 = (b & 127) * 64;
  const int hh = b >> 7;
  const int n0 = hh * 64;
  const int l15 = lane & 15, kl = (lane >> 4) * 8;

  const unsigned short* arow = xbf + (size_t)(g0 + w * 16 + l15) * 256 + kl;
  const unsigned short* brow = Wbf + (size_t)(n0 + l15) * 256 + kl;

  f32x4 acc[4];
#pragma unroll
  for (int nf = 0; nf < 4; ++nf) acc[nf] = zero4();

#pragma unroll
  for (int k = 0; k < 256; k += 32) {
    short8 a = *(const short8*)(arow + k);
#pragma unroll
    for (int nf = 0; nf < 4; ++nf) {
      short8 bb = *(const short8*)(brow + nf * 4096 + k);
      acc[nf] = MFMA16(a, bb, acc[nf]);
    }
  }

  const int rbase = w * 16 + (lane >> 4) * 4;
#pragma unroll
  for (int nf = 0; nf < 4; ++nf)
#pragma unroll
    for (int r = 0; r < 4; ++r)
      tile[rbase + r][nf * 16 + l15] = acc[nf][r];
  __syncthreads();

  const int bh = (g0 >> 11) * NHEAD + hh;
  // fragment-native bf16 write
  {
    const int dh = tid >> 2, nq = (tid & 3) * 16;
    const int c = ((g0 & 2047) + nq) >> 5;   // 32-j chunk within bh
    const int k0 = (nq & 16) >> 3;           // klg = 0 or 2 (v1 takes klg+1)
    unsigned short* dp = hTg + (size_t)bh * 131072 + c * 2048 + dh * 32 + k0 * 8;
    short8 v0, v1;
#pragma unroll
    for (int q = 0; q < 8; ++q) v0[q] = (short)f2bf(tile[nq + q][dh]);
#pragma unroll
    for (int q = 0; q < 8; ++q) v1[q] = (short)f2bf(tile[nq + 8 + q][dh]);
    *(short8*)dp = v0;
    *(short8*)(dp + 8) = v1;
  }
  // src/dst partial dot over dh
  {
    const int n_loc = tid & 63, q4 = tid >> 6;
    const float* as = a_src + hh * 64 + q4 * 16;
    const float* ad = a_dst + hh * 64 + q4 * 16;
    float ps = 0.f, pd = 0.f;
#pragma unroll
    for (int d2 = 0; d2 < 16; ++d2) {
      float hv = tile[n_loc][q4 * 16 + d2];
      ps += hv * as[d2];
      pd += hv * ad[d2];
    }
    reds[0][q4][n_loc] = ps;
    reds[1][q4][n_loc] = pd;
  }
  __syncthreads();
  if (tid < 64) {
    float s = reds[0][0][tid] + reds[0][1][tid] + reds[0][2][tid] + reds[0][3][tid];
    float d = reds[1][0][tid] + reds[1][1][tid] + reds[1][2][tid] + reds[1][3][tid];
    srcv[(size_t)bh * 2048 + (g0 & 2047) + tid] = s;
    dstv[(size_t)bh * 2048 + (g0 & 2047) + tid] = d;
  }
}

// ---------------- kernel 3: masked GAT attention (R9 proven body, verbatim) ----------------
// L2-direct kv (fragment-native hTg, contiguous 1KB wave-loads), no main-loop barriers.
// Max-form exp-free scores: p = mask ? max(A_i*B_j, C_i*D_j) : 0.
// __launch_bounds__(512,4): VGPR budget 128 — do NOT raise min-waves (R8: 295MB spill).
__global__ __launch_bounds__(512, 4) void k_attn(
    const unsigned short* __restrict__ hTg, const float* __restrict__ srcv,
    const float* __restrict__ dstv, const unsigned long long* __restrict__ bits,
    unsigned short* __restrict__ attb) {
  __shared__ float bB_s[2048];
  __shared__ float dD_s[2048];
  __shared__ unsigned long long adjw[64][33];
  __shared__ float src_s[64];
  __shared__ float red[8];
  __shared__ float comb[2][64][40];

  const int tid = threadIdx.x, lane = tid & 63, w = tid >> 6;
  const int orig = blockIdx.x;
  const int lid = (orig & 7) * 64 + (orig >> 3);  // XCD-bijective: 2 bh per XCD
  const int bh = lid >> 5;
  const int i0 = (lid & 31) * 64;
  const int rg = w & 1, js = w >> 1;
  const float LOG2E = 1.4426950408889634f;

  // ---- preamble: B/D tables + global dst max, src (scaled), adj words ----
  float lmax = -3.0e38f;
  {
    const float* dsrc = dstv + (size_t)bh * 2048;
    int idx = tid * 4;
    float4 v = *(const float4*)(dsrc + idx);
    v.x *= LOG2E; v.y *= LOG2E; v.z *= LOG2E; v.w *= LOG2E;
    lmax = fmaxf(fmaxf(v.x, v.y), fmaxf(v.z, v.w));
    float4 Bv, Dv;
    Bv.x = EXP2(v.x); Bv.y = EXP2(v.y); Bv.z = EXP2(v.z); Bv.w = EXP2(v.w);
    Dv.x = EXP2(0.2f * v.x); Dv.y = EXP2(0.2f * v.y);
    Dv.z = EXP2(0.2f * v.z); Dv.w = EXP2(0.2f * v.w);
    *(float4*)(bB_s + idx) = Bv;
    *(float4*)(dD_s + idx) = Dv;
#pragma unroll
    for (int off = 32; off >= 1; off >>= 1) lmax = fmaxf(lmax, __shfl_xor(lmax, off));
    if (lane == 0) red[w] = lmax;
    if (tid < 64) src_s[tid] = srcv[(size_t)bh * 2048 + i0 + tid] * LOG2E;
#pragma unroll
    for (int t = 0; t < 4; ++t) {
      int q = tid + t * 512;  // 0..2047
      adjw[q >> 5][q & 31] = bits[(size_t)(i0 + (q >> 5)) * 32 + (q & 31)];
    }
  }
  __syncthreads();
  const float dmax = fmaxf(fmaxf(fmaxf(red[0], red[1]), fmaxf(red[2], red[3])),
                           fmaxf(fmaxf(red[4], red[5]), fmaxf(red[6], red[7])));

  const int l15 = lane & 15, klg = lane >> 4, kl = klg * 8;
  const float src0 = src_s[rg * 32 + l15];
  const float src1 = src_s[rg * 32 + 16 + l15];
  const float sa0 = src0 + dmax, sa1 = src1 + dmax;
  const float m0 = fmaxf(sa0, 0.2f * sa0);  // scaled leaky upper bound of row max
  const float m1 = fmaxf(sa1, 0.2f * sa1);
  const float A0 = EXP2(src0 - m0), C0 = EXP2(fmaf(0.2f, src0, -m0));
  const float A1 = EXP2(src1 - m1), C1 = EXP2(fmaf(0.2f, src1, -m1));
  const int il0 = rg * 32 + l15, il1 = il0 + 16;
  const int wsel = js >> 1, wsh = (js & 1) * 32 + kl;

  const unsigned short* hgb = hTg + (size_t)bh * 131072;
  const int fragoff = l15 * 32 + klg * 8;  // +nf*512 per dh-quadrant

  short8 ones;
#pragma unroll
  for (int q = 0; q < 8; ++q) ones[q] = (short)0x3F80;

  f32x4 acc[2][4], accs[2];
#pragma unroll
  for (int rh = 0; rh < 2; ++rh) {
    accs[rh] = zero4();
#pragma unroll
    for (int nf = 0; nf < 4; ++nf) acc[rh][nf] = zero4();
  }

  // preload tile 0 fragments (contiguous 1KB wave-loads from L2)
  short8 pA0, pA1, pA2, pA3, pB0, pB1, pB2, pB3;
  {
    const unsigned short* kp = hgb + js * 2048 + fragoff;
    pA0 = *(const short8*)(kp);
    pA1 = *(const short8*)(kp + 512);
    pA2 = *(const short8*)(kp + 1024);
    pA3 = *(const short8*)(kp + 1536);
  }

#define GAT_TILE(T, C0_, C1_, C2_, C3_, N0_, N1_, N2_, N3_)                       \
  {                                                                               \
    if ((T) < 15) {                                                               \
      const unsigned short* kp = hgb + (((T) + 1) * 4 + js) * 2048 + fragoff;     \
      N0_ = *(const short8*)(kp);                                                 \
      N1_ = *(const short8*)(kp + 512);                                           \
      N2_ = *(const short8*)(kp + 1024);                                          \
      N3_ = *(const short8*)(kp + 1536);                                          \
    }                                                                             \
    const int jo = (T) * 128 + js * 32 + kl;                                      \
    float4 b0 = *(const float4*)(bB_s + jo);                                      \
    float4 b1 = *(const float4*)(bB_s + jo + 4);                                  \
    float4 e0 = *(const float4*)(dD_s + jo);                                      \
    float4 e1 = *(const float4*)(dD_s + jo + 4);                                  \
    float bv[8] = {b0.x, b0.y, b0.z, b0.w, b1.x, b1.y, b1.z, b1.w};               \
    float dq[8] = {e0.x, e0.y, e0.z, e0.w, e1.x, e1.y, e1.z, e1.w};               \
    const unsigned long long w0_ = adjw[il0][2 * (T) + wsel];                     \
    const unsigned long long w1_ = adjw[il1][2 * (T) + wsel];                     \
    {                                                                             \
      const unsigned int byte = (unsigned int)(w0_ >> wsh) & 0xFFu;               \
      float p[8];                                                                 \
      _Pragma("unroll") for (int t8 = 0; t8 < 8; ++t8) {                          \
        const float pv = fmaxf(A0 * bv[t8], C0 * dq[t8]);                         \
        p[t8] = ((byte >> t8) & 1u) ? pv : 0.f;                                   \
      }                                                                           \
      union { short8 s8; unsigned int u32[4]; } af;                               \
      _Pragma("unroll") for (int q = 0; q < 4; ++q)                               \
        asm("v_cvt_pk_bf16_f32 %0, %1, %2"                                       \
            : "=v"(af.u32[q]) : "v"(p[2 * q]), "v"(p[2 * q + 1]));                \
      accs[0] = MFMA16(af.s8, ones, accs[0]);                                     \
      acc[0][0] = MFMA16(af.s8, C0_, acc[0][0]);                                  \
      acc[0][1] = MFMA16(af.s8, C1_, acc[0][1]);                                  \
      acc[0][2] = MFMA16(af.s8, C2_, acc[0][2]);                                  \
      acc[0][3] = MFMA16(af.s8, C3_, acc[0][3]);                                  \
    }                                                                             \
    {                                                                             \
      const unsigned int byte = (unsigned int)(w1_ >> wsh) & 0xFFu;               \
      float p[8];                                                                 \
      _Pragma("unroll") for (int t8 = 0; t8 < 8; ++t8) {                          \
        const float pv = fmaxf(A1 * bv[t8], C1 * dq[t8]);                         \
        p[t8] = ((byte >> t8) & 1u) ? pv : 0.f;                                   \
      }                                                                           \
      union { short8 s8; unsigned int u32[4]; } af;                               \
      _Pragma("unroll") for (int q = 0; q < 4; ++q)                               \
        asm("v_cvt_pk_bf16_f32 %0, %1, %2"                                       \
            : "=v"(af.u32[q]) : "v"(p[2 * q]), "v"(p[2 * q + 1]));                \
      accs[1] = MFMA16(af.s8, ones, accs[1]);                                     \
      acc[1][0] = MFMA16(af.s8, C0_, acc[1][0]);                                  \
      acc[1][1] = MFMA16(af.s8, C1_, acc[1][1]);                                  \
      acc[1][2] = MFMA16(af.s8, C2_, acc[1][2]);                                  \
      acc[1][3] = MFMA16(af.s8, C3_, acc[1][3]);                                  \
    }                                                                             \
  }

#pragma unroll 1
  for (int tt = 0; tt < 16; tt += 2) {
    GAT_TILE(tt, pA0, pA1, pA2, pA3, pB0, pB1, pB2, pB3);
    GAT_TILE(tt + 1, pB0, pB1, pB2, pB3, pA0, pA1, pA2, pA3);
  }
#undef GAT_TILE

  // ---- combine j-slices (js=1..3 into js=0) ----
#pragma unroll 1
  for (int s = 1; s < 4; ++s) {
    if (js == s) {
#pragma unroll
      for (int rh = 0; rh < 2; ++rh) {
#pragma unroll
        for (int nf = 0; nf < 4; ++nf)
#pragma unroll
          for (int r = 0; r < 4; ++r) comb[rg][lane][rh * 20 + nf * 4 + r] = acc[rh][nf][r];
#pragma unroll
        for (int r = 0; r < 4; ++r) comb[rg][lane][rh * 20 + 16 + r] = accs[rh][r];
      }
    }
    __syncthreads();
    if (js == 0) {
#pragma unroll
      for (int rh = 0; rh < 2; ++rh) {
#pragma unroll
        for (int nf = 0; nf < 4; ++nf)
#pragma unroll
          for (int r = 0; r < 4; ++r) acc[rh][nf][r] += comb[rg][lane][rh * 20 + nf * 4 + r];
#pragma unroll
        for (int r = 0; r < 4; ++r) accs[rh][r] += comb[rg][lane][rh * 20 + 16 + r];
      }
    }
    __syncthreads();
  }

  // ---- epilogue: normalize + store (js==0 waves only) ----
  if (js == 0) {
    const int rb = klg * 4;
    const int b = bh >> 2, hh2 = bh & 3;
#pragma unroll
    for (int rh = 0; rh < 2; ++rh) {
      float linv[4];
#pragma unroll
      for (int r = 0; r < 4; ++r) linv[r] = 1.f / accs[rh][r];
#pragma unroll
      for (int nf = 0; nf < 4; ++nf)
#pragma unroll
        for (int r = 0; r < 4; ++r) {
          int i = i0 + rg * 32 + rh * 16 + rb + r;
          size_t o = ((size_t)(b * 2048 + i)) * 256 + hh2 * 64 + nf * 16 + l15;
          attb[o] = f2bf(acc[rh][nf][r] * linv[r]);
        }
    }
  }
}

// ---------------- kernel 4: out2 = att @ Wo^T + bo; y = LN(x + out2) ----------------
// Proven 256-thread body (R7/R9/R10). Do NOT re-split: the 512-thread 16-row variant
// failed correctness twice-unexplained (R11, absmax 0.148).
__global__ void k_gemm2(const unsigned short* __restrict__ attb, const unsigned short* __restrict__ Wobf,
                        const float* __restrict__ bo, const float* __restrict__ x,
                        const float* __restrict__ gamma, const float* __restrict__ beta,
                        float* __restrict__ out) {
  __shared__ float tile[32][260];
  const int tid = threadIdx.x, lane = tid & 63, w = tid >> 6;
  const int g0 = blockIdx.x * 32;
  const int l15 = lane & 15, kl = (lane >> 4) * 8;
  const int rw = (w & 1) * 16;
  const int cb = (w >> 1) * 128;

  const unsigned short* arow = attb + (size_t)(g0 + rw + l15) * 256 + kl;
  const unsigned short* brow = Wobf + (size_t)(cb + l15) * 256 + kl;

  f32x4 acc[8];
#pragma unroll
  for (int nf = 0; nf < 8; ++nf) acc[nf] = zero4();

#pragma unroll
  for (int k = 0; k < 256; k += 32) {
    short8 a = *(const short8*)(arow + k);
#pragma unroll
    for (int nf = 0; nf < 8; ++nf) {
      short8 b = *(const short8*)(brow + (size_t)nf * 4096 + k);
      acc[nf] = MFMA16(a, b, acc[nf]);
    }
  }

  const int rb = rw + (lane >> 4) * 4;
#pragma unroll
  for (int nf = 0; nf < 8; ++nf)
#pragma unroll
    for (int r = 0; r < 4; ++r) {
      int c = cb + nf * 16 + l15;
      tile[rb + r][c] = acc[nf][r] + bo[c];
    }
  __syncthreads();

  const float4 gv = *(const float4*)(gamma + lane * 4);
  const float4 bv = *(const float4*)(beta + lane * 4);
  for (int r = 0; r < 8; ++r) {
    const int gl = w * 8 + r;
    const size_t g = g0 + gl;
    float4 xv = *(const float4*)(x + g * 256 + lane * 4);
    float4 tv = *(float4*)(&tile[gl][lane * 4]);
    float v0 = tv.x + xv.x, v1 = tv.y + xv.y, v2 = tv.z + xv.z, v3 = tv.w + xv.w;
    float sum = v0 + v1 + v2 + v3;
    float sq = v0 * v0 + v1 * v1 + v2 * v2 + v3 * v3;
#pragma unroll
    for (int off = 32; off >= 1; off >>= 1) {
      sum += __shfl_xor(sum, off);
      sq += __shfl_xor(sq, off);
    }
    const float mu = sum * (1.f / 256.f);
    const float var = sq * (1.f / 256.f) - mu * mu;
    const float rs = rsqrtf(var + 1e-5f);
    float4 o;
    o.x = (v0 - mu) * rs * gv.x + bv.x;
    o.y = (v1 - mu) * rs * gv.y + bv.y;
    o.z = (v2 - mu) * rs * gv.z + bv.z;
    o.w = (v3 - mu) * rs * gv.w + bv.w;
    *(float4*)(out + g * 256 + lane * 4) = o;
  }
}

extern "C" void kernel_launch(void* const* d_in, const int* in_sizes, int n_in,
                              void* d_out, int out_size, void* d_ws, size_t ws_size,
                              hipStream_t stream) {
  const float* x      = (const float*)d_in[0];
  const int*   adj    = (const int*)d_in[1];
  const float* W      = (const float*)d_in[2];
  const float* a_src  = (const float*)d_in[3];
  const float* a_dst  = (const float*)d_in[4];
  const float* Wo     = (const float*)d_in[5];
  const float* bo     = (const float*)d_in[6];
  const float* gamma  = (const float*)d_in[7];
  const float* beta   = (const float*)d_in[8];
  float* out = (float*)d_out;

  char* ws = (char*)d_ws;
  unsigned short* xbf       = (unsigned short*)(ws);
  unsigned short* hTg       = (unsigned short*)(ws + (4u << 20));
  unsigned short* attb      = (unsigned short*)(ws + (8u << 20));
  unsigned long long* bits  = (unsigned long long*)(ws + (12u << 20));
  unsigned short* Wbf       = (unsigned short*)(ws + (12u << 20) + (512u << 10));
  unsigned short* Wobf      = (unsigned short*)(ws + (12u << 20) + (640u << 10));
  float* srcv               = (float*)(ws + (12u << 20) + (768u << 10));
  float* dstv               = (float*)(ws + (12u << 20) + (896u << 10));

  k_prep<<<2176, 256, 0, stream>>>(x, W, Wo, xbf, Wbf, Wobf);
  k_g1p<<<4608, 256, 0, stream>>>(xbf, Wbf, a_src, a_dst, adj, hTg, srcv, dstv, bits);
  k_attn<<<512, 512, 0, stream>>>(hTg, srcv, dstv, bits, attb);
  k_gemm2<<<256, 256, 0, stream>>>(attb, Wobf, bo, x, gamma, beta, out);
}